// Round 13
// baseline (519.169 us; speedup 1.0000x reference)
//
#include <hip/hip_runtime.h>

#define N_NODES 100000
#define N_EDGES 1600000
#define N_GRAPH 2000
#define INC 9
#define HID 256
#define OUTC 128
#define BN_EPS 1e-5f
#define SCAN_CHUNK 1024
#define NSCAN ((N_NODES + SCAN_CHUNK - 1) / SCAN_CHUNK)
#define SP_NODES 64
#define SP_BLOCKS ((N_NODES + SP_NODES - 1) / SP_NODES)   // 1563
#define NPART (2 * SP_BLOCKS)                              // 3126
#define RED_CHUNK ((NPART + 7) / 8)                        // 391

typedef unsigned int uint;
typedef unsigned short ushort;
typedef short bf16x8 __attribute__((ext_vector_type(8)));
typedef float f32x4 __attribute__((ext_vector_type(4)));

static __device__ inline ushort f2bf(float f) {
    uint u = __float_as_uint(f);
    uint r = (u + 0x7fffu + ((u >> 16) & 1u)) >> 16;
    return (ushort)r;
}
static __device__ inline float bflo(uint p) { return __uint_as_float(p << 16); }
static __device__ inline float bfhi(uint p) { return __uint_as_float(p & 0xffff0000u); }

// ---------------- CSR build ----------------

__global__ __launch_bounds__(256) void k_hist(const int* dst, int* degi) {
    int e = blockIdx.x * 256 + threadIdx.x;
    if (e < N_EDGES) atomicAdd(&degi[dst[e]], 1);
}

// scan1 also computes dis = rsqrt(deg+1)
__global__ __launch_bounds__(256) void k_scan1(const int* degi, int* exloc, int* bsum,
                                               float* dis) {
    __shared__ int s[SCAN_CHUNK];
    int t = threadIdx.x;
    int base = blockIdx.x * SCAN_CHUNK;
#pragma unroll
    for (int j = 0; j < 4; ++j) {
        int i = t + j * 256;
        int gi = base + i;
        int dv = (gi < N_NODES) ? degi[gi] : 0;
        s[i] = dv;
        if (gi < N_NODES) dis[gi] = rsqrtf((float)(dv + 1));
    }
    __syncthreads();
    for (int off = 1; off < SCAN_CHUNK; off <<= 1) {
        int v_[4];
#pragma unroll
        for (int j = 0; j < 4; ++j) {
            int i = t + j * 256;
            v_[j] = (i >= off) ? s[i - off] : 0;
        }
        __syncthreads();
#pragma unroll
        for (int j = 0; j < 4; ++j) s[t + j * 256] += v_[j];
        __syncthreads();
    }
#pragma unroll
    for (int j = 0; j < 4; ++j) {
        int i = t + j * 256;
        int gi = base + i;
        if (gi < N_NODES) exloc[gi] = i ? s[i - 1] : 0;
    }
    if (t == 0) bsum[blockIdx.x] = s[SCAN_CHUNK - 1];
}

__global__ void k_scan2(int* bsum) {
    if (threadIdx.x == 0 && blockIdx.x == 0) {
        int acc = 0;
        for (int i = 0; i < NSCAN; ++i) { int v = bsum[i]; bsum[i] = acc; acc += v; }
    }
}

__global__ __launch_bounds__(256) void k_scan3(const int* exloc, const int* bsum,
                                               int* row_start) {
    int v = blockIdx.x * 256 + threadIdx.x;
    if (v < N_NODES) row_start[v] = exloc[v] + bsum[v >> 10];
}

// AoS CSR: one 8B store per edge {src, weight}
__global__ __launch_bounds__(256) void k_scatter(const int* src, const int* dst,
                                                 const float* dis, const int* row_start,
                                                 int* cursor, int2* csr) {
    int e = blockIdx.x * 256 + threadIdx.x;
    if (e < N_EDGES) {
        int s = src[e], d = dst[e];
        int pos = row_start[d] + atomicAdd(&cursor[d], 1);
        csr[pos] = make_int2(s, __float_as_int(dis[s] * dis[d]));
    }
}

// ---------------- W2 transpose + bf16 convert (once per call) ----------------

__global__ __launch_bounds__(256) void k_w2t(const float* W2, ushort* W2Tg) {
    int i = blockIdx.x * 256 + threadIdx.x;       // [0, HID*OUTC)
    if (i < HID * OUTC) {
        int col = i >> 8;        // OUTC index
        int k = i & 255;         // HID index
        W2Tg[i] = f2bf(W2[k * OUTC + col]);
    }
}

// ---------------- conv1 aggregation (gather, 9-wide, self fused) ----------------

__global__ __launch_bounds__(256) void k_gather9(const float* x, const float* dis,
                                                 const int* row_start, const int* degi,
                                                 const int2* csr,
                                                 float* aggx) {
    int t = threadIdx.x;
    if (t >= 252) return;
    int v = blockIdx.x * 28 + t / 9;
    if (v >= N_NODES) return;
    int c = t % 9;
    float w = dis[v];
    float acc = w * w * x[v * INC + c];
    int r0 = row_start[v], dn = degi[v];
    for (int e = 0; e < dn; ++e) {
        int2 ed = csr[r0 + e];
        acc = fmaf(__int_as_float(ed.y), x[ed.x * INC + c], acc);
    }
    aggx[v * INC + c] = acc;
}

// ---------------- BN1 stats: recompute h1 = aggx @ W1 on the fly ----------------

__global__ __launch_bounds__(256) void k_stats1(const float* aggx, const float* W1,
                                                double* stats) {
    __shared__ float sx[128][INC];
    int c = threadIdx.x;
    int v0 = blockIdx.x * 128;
    for (int i = threadIdx.x; i < 128 * INC; i += 256) {
        int vv = i / INC, cc = i % INC;
        int v = v0 + vv;
        sx[vv][cc] = (v < N_NODES) ? aggx[v * INC + cc] : 0.0f;
    }
    __syncthreads();
    float w[INC];
#pragma unroll
    for (int k = 0; k < INC; ++k) w[k] = W1[k * HID + c];
    double s = 0.0, s2 = 0.0;
    int nmax = min(128, N_NODES - v0);
    for (int n = 0; n < nmax; ++n) {
        float h = 0.0f;
#pragma unroll
        for (int k = 0; k < INC; ++k) h = fmaf(sx[n][k], w[k], h);
        s += (double)h;
        s2 += (double)h * (double)h;
    }
    atomicAdd(&stats[c], s);
    atomicAdd(&stats[HID + c], s2);
}

__global__ void k_finalize(const double* stats, const float* g, const float* be,
                           float* a, float* d, int C) {
    int c = blockIdx.x * blockDim.x + threadIdx.x;
    if (c < C) {
        const double invN = 1.0 / (double)N_NODES;
        float mean = (float)(stats[c] * invN);
        float ex2  = (float)(stats[C + c] * invN);
        float var  = ex2 - mean * mean;
        float istd = rsqrtf(var + BN_EPS);
        a[c] = istd * g[c];
        d[c] = be[c] - mean * istd * g[c];
    }
}

// ---------------- GEMM2 (MFMA): z = relu(bn1(aggx@W1)) @ W2, bf16 in/out -------------

#define HPAD 88

__global__ __launch_bounds__(256) void k_gemm2_mfma(const float* aggx, const float* W1,
                                                    const ushort* W2Tg, const float* a1,
                                                    const float* d1, ushort* z) {
    __shared__ __align__(16) unsigned char smem[47616];
    ushort* sHb  = (ushort*)(smem);                 // [64][88]  11264 B
    ushort* sW2T = (ushort*)(smem + 11264);         // [128][88] 22528 B
    float*  sW1f = (float*) (smem + 33792);         // [9*256]    9216 B
    float*  sA   = (float*) (smem + 43008);         // [64][9]    2304 B
    float*  sa1  = (float*) (smem + 45312);         // [256]      1024 B
    float*  sd1  = (float*) (smem + 46336);         // [256]      1024 B

    int t = threadIdx.x;
    int v0 = blockIdx.x * 64;

    for (int i = t; i < INC * HID; i += 256) sW1f[i] = W1[i];
    sa1[t] = a1[t & 255];
    sd1[t] = d1[t & 255];
    for (int i = t; i < 64 * INC; i += 256) {
        int vv = i / INC, cc = i % INC;
        int v = v0 + vv;
        sA[i] = (v < N_NODES) ? aggx[v * INC + cc] : 0.0f;
    }
    __syncthreads();

    int row = t >> 2, q = t & 3;
    int wave = t >> 6, lane = t & 63;
    int lr = lane & 15, lq = lane >> 4;

    float ax[INC];
#pragma unroll
    for (int k = 0; k < INC; ++k) ax[k] = sA[row * INC + k];

    f32x4 acc[8];
#pragma unroll
    for (int ct = 0; ct < 8; ++ct) acc[ct] = (f32x4){0.f, 0.f, 0.f, 0.f};

    for (int k0 = 0; k0 < HID; k0 += 64) {
#pragma unroll
        for (int i = 0; i < 4; ++i) {
            int idx = t + i * 256;
            int col = idx >> 3, sub = idx & 7;
            *(uint4*)&sW2T[col * HPAD + sub * 8] =
                *(const uint4*)&W2Tg[col * HID + k0 + sub * 8];
        }
#pragma unroll
        for (int jj = 0; jj < 8; ++jj) {
            int gc = k0 + q * 16 + jj * 2;
            float h0 = 0.f, h1 = 0.f;
#pragma unroll
            for (int k = 0; k < INC; ++k) {
                h0 = fmaf(ax[k], sW1f[k * HID + gc], h0);
                h1 = fmaf(ax[k], sW1f[k * HID + gc + 1], h1);
            }
            float hn0 = fmaxf(fmaf(h0, sa1[gc], sd1[gc]), 0.f);
            float hn1 = fmaxf(fmaf(h1, sa1[gc + 1], sd1[gc + 1]), 0.f);
            uint pk = (uint)f2bf(hn0) | ((uint)f2bf(hn1) << 16);
            *(uint*)&sHb[row * HPAD + q * 16 + jj * 2] = pk;
        }
        __syncthreads();
        int arow = (wave * 16 + lr) * HPAD + lq * 8;
        bf16x8 a0 = *(const bf16x8*)&sHb[arow];
        bf16x8 a1v = *(const bf16x8*)&sHb[arow + 32];
#pragma unroll
        for (int ct = 0; ct < 8; ++ct) {
            int brow = (ct * 16 + lr) * HPAD + lq * 8;
            bf16x8 b0 = *(const bf16x8*)&sW2T[brow];
            bf16x8 b1 = *(const bf16x8*)&sW2T[brow + 32];
            acc[ct] = __builtin_amdgcn_mfma_f32_16x16x32_bf16(a0, b0, acc[ct], 0, 0, 0);
            acc[ct] = __builtin_amdgcn_mfma_f32_16x16x32_bf16(a1v, b1, acc[ct], 0, 0, 0);
        }
        __syncthreads();
    }

    ushort* stage = (ushort*)smem;                  // [64][128]
#pragma unroll
    for (int ct = 0; ct < 8; ++ct)
#pragma unroll
        for (int r = 0; r < 4; ++r)
            stage[(wave * 16 + lq * 4 + r) * 128 + ct * 16 + lr] = f2bf(acc[ct][r]);
    __syncthreads();
#pragma unroll
    for (int i = 0; i < 4; ++i) {
        int idx = t + i * 256;
        int rr = idx >> 4, sub = idx & 15;
        int v = v0 + rr;
        if (v < N_NODES)
            *(uint4*)&z[(size_t)v * OUTC + sub * 8] =
                *(const uint4*)&stage[rr * 128 + sub * 8];
    }
}

// ---------------- conv2 aggregation (gather, bf16 z, 16 rows x 16 lanes) ----------------

__global__ __launch_bounds__(256) void k_gather128(const ushort* z, const float* dis,
                                                   const int* row_start, const int* degi,
                                                   const int2* csr,
                                                   float* agg2) {
    int t = threadIdx.x;
    int v = blockIdx.x * 16 + (t >> 4);
    if (v >= N_NODES) return;
    int c0 = (t & 15) * 8;

    float acc[8];
    float dv = dis[v];
    float w2 = dv * dv;
    uint4 zv = *(const uint4*)&z[(size_t)v * OUTC + c0];
    acc[0] = w2 * bflo(zv.x); acc[1] = w2 * bfhi(zv.x);
    acc[2] = w2 * bflo(zv.y); acc[3] = w2 * bfhi(zv.y);
    acc[4] = w2 * bflo(zv.z); acc[5] = w2 * bfhi(zv.z);
    acc[6] = w2 * bflo(zv.w); acc[7] = w2 * bfhi(zv.w);

    int r0 = row_start[v], dn = degi[v];
    for (int e = 0; e < dn; ++e) {
        int2 ed = csr[r0 + e];
        float ew = __int_as_float(ed.y);
        uint4 sv = *(const uint4*)&z[(size_t)ed.x * OUTC + c0];
        acc[0] = fmaf(ew, bflo(sv.x), acc[0]);
        acc[1] = fmaf(ew, bfhi(sv.x), acc[1]);
        acc[2] = fmaf(ew, bflo(sv.y), acc[2]);
        acc[3] = fmaf(ew, bfhi(sv.y), acc[3]);
        acc[4] = fmaf(ew, bflo(sv.z), acc[4]);
        acc[5] = fmaf(ew, bfhi(sv.z), acc[5]);
        acc[6] = fmaf(ew, bflo(sv.w), acc[6]);
        acc[7] = fmaf(ew, bfhi(sv.w), acc[7]);
    }
    float4 lo = make_float4(acc[0], acc[1], acc[2], acc[3]);
    float4 hi = make_float4(acc[4], acc[5], acc[6], acc[7]);
    *(float4*)&agg2[(size_t)v * OUTC + c0] = lo;
    *(float4*)&agg2[(size_t)v * OUTC + c0 + 4] = hi;
}

// ---------------- fused BN2 stats + pool: partials to scratch (no hot atomics) --------
// 256 thr, 64 nodes/block in two 32-row halves; per-(block,half) f64 partials written
// non-atomically to part[p][256]; k_stats_red reduces with 8 atomics/address.

__global__ __launch_bounds__(256) void k_stats_pool(const float* agg2, const int* batch,
                                                    double* part, float* psum, float* pcnt) {
    int t = threadIdx.x;
    int c = t & 127;
    int half = t >> 7;                      // 0 or 1
    int p = blockIdx.x * 2 + half;
    int v0 = blockIdx.x * SP_NODES + half * (SP_NODES / 2);
    double s = 0.0, s2 = 0.0;
    if (v0 < N_NODES) {
        int vend = min(v0 + SP_NODES / 2, N_NODES);
        float acc = 0.0f;
        int cnt = 0;
        int gprev = batch[v0];
        for (int v = v0; v < vend; ++v) {
            float h = agg2[(size_t)v * OUTC + c];
            s += (double)h;
            s2 += (double)h * (double)h;
            int g = batch[v];
            if (g != gprev) {
                atomicAdd(&psum[gprev * OUTC + c], acc);
                if (c == 0) atomicAdd(&pcnt[gprev], (float)cnt);
                acc = 0.0f; cnt = 0; gprev = g;
            }
            acc += h;
            cnt++;
        }
        atomicAdd(&psum[gprev * OUTC + c], acc);
        if (c == 0) atomicAdd(&pcnt[gprev], (float)cnt);
    }
    part[(size_t)p * 256 + c]       = s;    // zeros for out-of-range tiles
    part[(size_t)p * 256 + 128 + c] = s2;
}

__global__ __launch_bounds__(256) void k_stats_red(const double* part, double* stats) {
    int t = threadIdx.x;
    int p0 = blockIdx.x * RED_CHUNK;
    int pe = min(p0 + RED_CHUNK, NPART);
    double s = 0.0;
    for (int p = p0; p < pe; ++p) s += part[(size_t)p * 256 + t];
    atomicAdd(&stats[t], s);                // stats[0..127]=sum, [128..255]=sum2
}

// ---------------- output: affine + mean + L2 normalize ----------------

__global__ __launch_bounds__(128) void k_out(const float* psum, const float* pcnt,
                                             const float* a2, const float* d2,
                                             float* out) {
    int g = blockIdx.x;
    int c = threadIdx.x;
    float cnt = fmaxf(pcnt[g], 1.0f);
    float m = fmaf(psum[g * OUTC + c] / cnt, a2[c], d2[c]);
    float ss = m * m;
#pragma unroll
    for (int o = 1; o < 64; o <<= 1) ss += __shfl_xor(ss, o);
    __shared__ float ws[2];
    if ((c & 63) == 0) ws[c >> 6] = ss;
    __syncthreads();
    float nrm = sqrtf(ws[0] + ws[1]);
    out[g * OUTC + c] = m / fmaxf(nrm, 1e-12f);
}

// ---------------- launch ----------------

extern "C" void kernel_launch(void* const* d_in, const int* in_sizes, int n_in,
                              void* d_out, int out_size, void* d_ws, size_t ws_size,
                              hipStream_t stream) {
    const float* x   = (const float*)d_in[0];
    const float* W1  = (const float*)d_in[1];
    const float* g1  = (const float*)d_in[3];
    const float* be1 = (const float*)d_in[4];
    const float* W2  = (const float*)d_in[5];
    const float* g2  = (const float*)d_in[7];
    const float* be2 = (const float*)d_in[8];
    const int* ei    = (const int*)d_in[9];
    const int* batch = (const int*)d_in[10];
    const int* src = ei;
    const int* dst = ei + N_EDGES;
    float* out = (float*)d_out;

    char* ws = (char*)d_ws;
    size_t off = 0;
    auto alloc = [&](size_t b) {
        char* p = ws + off;
        off = (off + b + 255) & ~(size_t)255;
        return p;
    };
    float*  dis   = (float*)alloc((size_t)N_NODES * 4);
    int*    degi  = (int*)  alloc((size_t)N_NODES * 4);
    int*    curs  = (int*)  alloc((size_t)N_NODES * 4);
    int*    exloc = (int*)  alloc((size_t)N_NODES * 4);
    int*    rowst = (int*)  alloc((size_t)N_NODES * 4);
    int*    bsum  = (int*)  alloc((size_t)NSCAN * 4);
    int2*   csr   = (int2*) alloc((size_t)N_EDGES * 8);
    float*  aggx  = (float*)alloc((size_t)N_NODES * INC * 4);
    ushort* z     = (ushort*)alloc((size_t)N_NODES * OUTC * 2);
    ushort* w2t   = (ushort*)alloc((size_t)HID * OUTC * 2);
    float*  agg2  = (float*)alloc((size_t)N_NODES * OUTC * 4);
    double* part  = (double*)alloc((size_t)NPART * 256 * 8);
    double* st1   = (double*)alloc(2 * HID * 8);
    double* st2   = (double*)alloc(2 * OUTC * 8);
    float*  a1    = (float*)alloc(HID * 4);
    float*  d1    = (float*)alloc(HID * 4);
    float*  a2    = (float*)alloc(OUTC * 4);
    float*  d2    = (float*)alloc(OUTC * 4);
    float*  psum  = (float*)alloc((size_t)N_GRAPH * OUTC * 4);
    float*  pcnt  = (float*)alloc((size_t)N_GRAPH * 4);

    hipMemsetAsync(degi, 0, (size_t)N_NODES * 4, stream);
    hipMemsetAsync(curs, 0, (size_t)N_NODES * 4, stream);
    hipMemsetAsync(st1, 0, 2 * HID * 8, stream);
    hipMemsetAsync(st2, 0, 2 * OUTC * 8, stream);
    hipMemsetAsync(psum, 0, (size_t)N_GRAPH * OUTC * 4, stream);
    hipMemsetAsync(pcnt, 0, (size_t)N_GRAPH * 4, stream);

    k_hist<<<(N_EDGES + 255) / 256, 256, 0, stream>>>(dst, degi);
    k_scan1<<<NSCAN, 256, 0, stream>>>(degi, exloc, bsum, dis);
    k_scan2<<<1, 64, 0, stream>>>(bsum);
    k_scan3<<<(N_NODES + 255) / 256, 256, 0, stream>>>(exloc, bsum, rowst);
    k_scatter<<<(N_EDGES + 255) / 256, 256, 0, stream>>>(src, dst, dis, rowst, curs, csr);
    k_w2t<<<(HID * OUTC + 255) / 256, 256, 0, stream>>>(W2, w2t);
    k_gather9<<<(N_NODES + 27) / 28, 256, 0, stream>>>(x, dis, rowst, degi, csr, aggx);
    k_stats1<<<(N_NODES + 127) / 128, 256, 0, stream>>>(aggx, W1, st1);
    k_finalize<<<1, HID, 0, stream>>>(st1, g1, be1, a1, d1, HID);
    k_gemm2_mfma<<<(N_NODES + 63) / 64, 256, 0, stream>>>(aggx, W1, w2t, a1, d1, z);
    k_gather128<<<(N_NODES + 15) / 16, 256, 0, stream>>>(z, dis, rowst, degi, csr, agg2);
    k_stats_pool<<<SP_BLOCKS, 256, 0, stream>>>(agg2, batch, part, psum, pcnt);
    k_stats_red<<<8, 256, 0, stream>>>(part, st2);
    k_finalize<<<1, OUTC, 0, stream>>>(st2, g2, be2, a2, d2, OUTC);
    k_out<<<N_GRAPH, OUTC, 0, stream>>>(psum, pcnt, a2, d2, out);
}

// Round 14
// 437.000 us; speedup vs baseline: 1.1880x; 1.1880x over previous
//
#include <hip/hip_runtime.h>

#define N_NODES 100000
#define N_EDGES 1600000
#define N_GRAPH 2000
#define INC 9
#define HID 256
#define OUTC 128
#define BN_EPS 1e-5f
#define SCAN_CHUNK 1024
#define NSCAN ((N_NODES + SCAN_CHUNK - 1) / SCAN_CHUNK)
#define SP_NODES 64
#define SP_BLOCKS ((N_NODES + SP_NODES - 1) / SP_NODES)   // 1563
#define NPART (2 * SP_BLOCKS)                              // 3126

typedef unsigned int uint;
typedef unsigned short ushort;
typedef short bf16x8 __attribute__((ext_vector_type(8)));
typedef float f32x4 __attribute__((ext_vector_type(4)));

static __device__ inline ushort f2bf(float f) {
    uint u = __float_as_uint(f);
    uint r = (u + 0x7fffu + ((u >> 16) & 1u)) >> 16;
    return (ushort)r;
}
static __device__ inline float bflo(uint p) { return __uint_as_float(p << 16); }
static __device__ inline float bfhi(uint p) { return __uint_as_float(p & 0xffff0000u); }

// ---------------- CSR build ----------------

__global__ __launch_bounds__(256) void k_hist(const int* dst, int* degi) {
    int e = blockIdx.x * 256 + threadIdx.x;
    if (e < N_EDGES) atomicAdd(&degi[dst[e]], 1);
}

// scan1 also computes dis = rsqrt(deg+1)
__global__ __launch_bounds__(256) void k_scan1(const int* degi, int* exloc, int* bsum,
                                               float* dis) {
    __shared__ int s[SCAN_CHUNK];
    int t = threadIdx.x;
    int base = blockIdx.x * SCAN_CHUNK;
#pragma unroll
    for (int j = 0; j < 4; ++j) {
        int i = t + j * 256;
        int gi = base + i;
        int dv = (gi < N_NODES) ? degi[gi] : 0;
        s[i] = dv;
        if (gi < N_NODES) dis[gi] = rsqrtf((float)(dv + 1));
    }
    __syncthreads();
    for (int off = 1; off < SCAN_CHUNK; off <<= 1) {
        int v_[4];
#pragma unroll
        for (int j = 0; j < 4; ++j) {
            int i = t + j * 256;
            v_[j] = (i >= off) ? s[i - off] : 0;
        }
        __syncthreads();
#pragma unroll
        for (int j = 0; j < 4; ++j) s[t + j * 256] += v_[j];
        __syncthreads();
    }
#pragma unroll
    for (int j = 0; j < 4; ++j) {
        int i = t + j * 256;
        int gi = base + i;
        if (gi < N_NODES) exloc[gi] = i ? s[i - 1] : 0;
    }
    if (t == 0) bsum[blockIdx.x] = s[SCAN_CHUNK - 1];
}

__global__ void k_scan2(int* bsum) {
    if (threadIdx.x == 0 && blockIdx.x == 0) {
        int acc = 0;
        for (int i = 0; i < NSCAN; ++i) { int v = bsum[i]; bsum[i] = acc; acc += v; }
    }
}

__global__ __launch_bounds__(256) void k_scan3(const int* exloc, const int* bsum,
                                               int* row_start) {
    int v = blockIdx.x * 256 + threadIdx.x;
    if (v < N_NODES) row_start[v] = exloc[v] + bsum[v >> 10];
}

// AoS CSR: one 8B store per edge {src, weight}
__global__ __launch_bounds__(256) void k_scatter(const int* src, const int* dst,
                                                 const float* dis, const int* row_start,
                                                 int* cursor, int2* csr) {
    int e = blockIdx.x * 256 + threadIdx.x;
    if (e < N_EDGES) {
        int s = src[e], d = dst[e];
        int pos = row_start[d] + atomicAdd(&cursor[d], 1);
        csr[pos] = make_int2(s, __float_as_int(dis[s] * dis[d]));
    }
}

// ---------------- W2 transpose + bf16 convert (once per call) ----------------

__global__ __launch_bounds__(256) void k_w2t(const float* W2, ushort* W2Tg) {
    int i = blockIdx.x * 256 + threadIdx.x;       // [0, HID*OUTC)
    if (i < HID * OUTC) {
        int col = i >> 8;        // OUTC index
        int k = i & 255;         // HID index
        W2Tg[i] = f2bf(W2[k * OUTC + col]);
    }
}

// ---------------- conv1 aggregation (gather, 9-wide, self fused) ----------------

__global__ __launch_bounds__(256) void k_gather9(const float* x, const float* dis,
                                                 const int* row_start, const int* degi,
                                                 const int2* csr,
                                                 float* aggx) {
    int t = threadIdx.x;
    if (t >= 252) return;
    int v = blockIdx.x * 28 + t / 9;
    if (v >= N_NODES) return;
    int c = t % 9;
    float w = dis[v];
    float acc = w * w * x[v * INC + c];
    int r0 = row_start[v], dn = degi[v];
    for (int e = 0; e < dn; ++e) {
        int2 ed = csr[r0 + e];
        acc = fmaf(__int_as_float(ed.y), x[ed.x * INC + c], acc);
    }
    aggx[v * INC + c] = acc;
}

// ---------------- BN1 stats: recompute h1 = aggx @ W1 on the fly ----------------

__global__ __launch_bounds__(256) void k_stats1(const float* aggx, const float* W1,
                                                double* stats) {
    __shared__ float sx[128][INC];
    int c = threadIdx.x;
    int v0 = blockIdx.x * 128;
    for (int i = threadIdx.x; i < 128 * INC; i += 256) {
        int vv = i / INC, cc = i % INC;
        int v = v0 + vv;
        sx[vv][cc] = (v < N_NODES) ? aggx[v * INC + cc] : 0.0f;
    }
    __syncthreads();
    float w[INC];
#pragma unroll
    for (int k = 0; k < INC; ++k) w[k] = W1[k * HID + c];
    double s = 0.0, s2 = 0.0;
    int nmax = min(128, N_NODES - v0);
    for (int n = 0; n < nmax; ++n) {
        float h = 0.0f;
#pragma unroll
        for (int k = 0; k < INC; ++k) h = fmaf(sx[n][k], w[k], h);
        s += (double)h;
        s2 += (double)h * (double)h;
    }
    atomicAdd(&stats[c], s);
    atomicAdd(&stats[HID + c], s2);
}

__global__ void k_finalize(const double* stats, const float* g, const float* be,
                           float* a, float* d, int C) {
    int c = blockIdx.x * blockDim.x + threadIdx.x;
    if (c < C) {
        const double invN = 1.0 / (double)N_NODES;
        float mean = (float)(stats[c] * invN);
        float ex2  = (float)(stats[C + c] * invN);
        float var  = ex2 - mean * mean;
        float istd = rsqrtf(var + BN_EPS);
        a[c] = istd * g[c];
        d[c] = be[c] - mean * istd * g[c];
    }
}

// ---------------- GEMM2 (MFMA): z = relu(bn1(aggx@W1)) @ W2, bf16 in/out -------------

#define HPAD 88

__global__ __launch_bounds__(256) void k_gemm2_mfma(const float* aggx, const float* W1,
                                                    const ushort* W2Tg, const float* a1,
                                                    const float* d1, ushort* z) {
    __shared__ __align__(16) unsigned char smem[47616];
    ushort* sHb  = (ushort*)(smem);                 // [64][88]  11264 B
    ushort* sW2T = (ushort*)(smem + 11264);         // [128][88] 22528 B
    float*  sW1f = (float*) (smem + 33792);         // [9*256]    9216 B
    float*  sA   = (float*) (smem + 43008);         // [64][9]    2304 B
    float*  sa1  = (float*) (smem + 45312);         // [256]      1024 B
    float*  sd1  = (float*) (smem + 46336);         // [256]      1024 B

    int t = threadIdx.x;
    int v0 = blockIdx.x * 64;

    for (int i = t; i < INC * HID; i += 256) sW1f[i] = W1[i];
    sa1[t] = a1[t & 255];
    sd1[t] = d1[t & 255];
    for (int i = t; i < 64 * INC; i += 256) {
        int vv = i / INC, cc = i % INC;
        int v = v0 + vv;
        sA[i] = (v < N_NODES) ? aggx[v * INC + cc] : 0.0f;
    }
    __syncthreads();

    int row = t >> 2, q = t & 3;
    int wave = t >> 6, lane = t & 63;
    int lr = lane & 15, lq = lane >> 4;

    float ax[INC];
#pragma unroll
    for (int k = 0; k < INC; ++k) ax[k] = sA[row * INC + k];

    f32x4 acc[8];
#pragma unroll
    for (int ct = 0; ct < 8; ++ct) acc[ct] = (f32x4){0.f, 0.f, 0.f, 0.f};

    for (int k0 = 0; k0 < HID; k0 += 64) {
#pragma unroll
        for (int i = 0; i < 4; ++i) {
            int idx = t + i * 256;
            int col = idx >> 3, sub = idx & 7;
            *(uint4*)&sW2T[col * HPAD + sub * 8] =
                *(const uint4*)&W2Tg[col * HID + k0 + sub * 8];
        }
#pragma unroll
        for (int jj = 0; jj < 8; ++jj) {
            int gc = k0 + q * 16 + jj * 2;
            float h0 = 0.f, h1 = 0.f;
#pragma unroll
            for (int k = 0; k < INC; ++k) {
                h0 = fmaf(ax[k], sW1f[k * HID + gc], h0);
                h1 = fmaf(ax[k], sW1f[k * HID + gc + 1], h1);
            }
            float hn0 = fmaxf(fmaf(h0, sa1[gc], sd1[gc]), 0.f);
            float hn1 = fmaxf(fmaf(h1, sa1[gc + 1], sd1[gc + 1]), 0.f);
            uint pk = (uint)f2bf(hn0) | ((uint)f2bf(hn1) << 16);
            *(uint*)&sHb[row * HPAD + q * 16 + jj * 2] = pk;
        }
        __syncthreads();
        int arow = (wave * 16 + lr) * HPAD + lq * 8;
        bf16x8 a0 = *(const bf16x8*)&sHb[arow];
        bf16x8 a1v = *(const bf16x8*)&sHb[arow + 32];
#pragma unroll
        for (int ct = 0; ct < 8; ++ct) {
            int brow = (ct * 16 + lr) * HPAD + lq * 8;
            bf16x8 b0 = *(const bf16x8*)&sW2T[brow];
            bf16x8 b1 = *(const bf16x8*)&sW2T[brow + 32];
            acc[ct] = __builtin_amdgcn_mfma_f32_16x16x32_bf16(a0, b0, acc[ct], 0, 0, 0);
            acc[ct] = __builtin_amdgcn_mfma_f32_16x16x32_bf16(a1v, b1, acc[ct], 0, 0, 0);
        }
        __syncthreads();
    }

    ushort* stage = (ushort*)smem;                  // [64][128]
#pragma unroll
    for (int ct = 0; ct < 8; ++ct)
#pragma unroll
        for (int r = 0; r < 4; ++r)
            stage[(wave * 16 + lq * 4 + r) * 128 + ct * 16 + lr] = f2bf(acc[ct][r]);
    __syncthreads();
#pragma unroll
    for (int i = 0; i < 4; ++i) {
        int idx = t + i * 256;
        int rr = idx >> 4, sub = idx & 15;
        int v = v0 + rr;
        if (v < N_NODES)
            *(uint4*)&z[(size_t)v * OUTC + sub * 8] =
                *(const uint4*)&stage[rr * 128 + sub * 8];
    }
}

// ---------------- conv2 aggregation (gather, bf16 z, 16 rows x 16 lanes) ----------------

__global__ __launch_bounds__(256) void k_gather128(const ushort* z, const float* dis,
                                                   const int* row_start, const int* degi,
                                                   const int2* csr,
                                                   float* agg2) {
    int t = threadIdx.x;
    int v = blockIdx.x * 16 + (t >> 4);
    if (v >= N_NODES) return;
    int c0 = (t & 15) * 8;

    float acc[8];
    float dv = dis[v];
    float w2 = dv * dv;
    uint4 zv = *(const uint4*)&z[(size_t)v * OUTC + c0];
    acc[0] = w2 * bflo(zv.x); acc[1] = w2 * bfhi(zv.x);
    acc[2] = w2 * bflo(zv.y); acc[3] = w2 * bfhi(zv.y);
    acc[4] = w2 * bflo(zv.z); acc[5] = w2 * bfhi(zv.z);
    acc[6] = w2 * bflo(zv.w); acc[7] = w2 * bfhi(zv.w);

    int r0 = row_start[v], dn = degi[v];
    for (int e = 0; e < dn; ++e) {
        int2 ed = csr[r0 + e];
        float ew = __int_as_float(ed.y);
        uint4 sv = *(const uint4*)&z[(size_t)ed.x * OUTC + c0];
        acc[0] = fmaf(ew, bflo(sv.x), acc[0]);
        acc[1] = fmaf(ew, bfhi(sv.x), acc[1]);
        acc[2] = fmaf(ew, bflo(sv.y), acc[2]);
        acc[3] = fmaf(ew, bfhi(sv.y), acc[3]);
        acc[4] = fmaf(ew, bflo(sv.z), acc[4]);
        acc[5] = fmaf(ew, bfhi(sv.z), acc[5]);
        acc[6] = fmaf(ew, bflo(sv.w), acc[6]);
        acc[7] = fmaf(ew, bfhi(sv.w), acc[7]);
    }
    float4 lo = make_float4(acc[0], acc[1], acc[2], acc[3]);
    float4 hi = make_float4(acc[4], acc[5], acc[6], acc[7]);
    *(float4*)&agg2[(size_t)v * OUTC + c0] = lo;
    *(float4*)&agg2[(size_t)v * OUTC + c0 + 4] = hi;
}

// ---------------- fused BN2 stats + pool: partials to scratch (no hot atomics) --------

__global__ __launch_bounds__(256) void k_stats_pool(const float* agg2, const int* batch,
                                                    double* part, float* psum, float* pcnt) {
    int t = threadIdx.x;
    int c = t & 127;
    int half = t >> 7;                      // 0 or 1
    int p = blockIdx.x * 2 + half;
    int v0 = blockIdx.x * SP_NODES + half * (SP_NODES / 2);
    double s = 0.0, s2 = 0.0;
    if (v0 < N_NODES) {
        int vend = min(v0 + SP_NODES / 2, N_NODES);
        float acc = 0.0f;
        int cnt = 0;
        int gprev = batch[v0];
        for (int v = v0; v < vend; ++v) {
            float h = agg2[(size_t)v * OUTC + c];
            s += (double)h;
            s2 += (double)h * (double)h;
            int g = batch[v];
            if (g != gprev) {
                atomicAdd(&psum[gprev * OUTC + c], acc);
                if (c == 0) atomicAdd(&pcnt[gprev], (float)cnt);
                acc = 0.0f; cnt = 0; gprev = g;
            }
            acc += h;
            cnt++;
        }
        atomicAdd(&psum[gprev * OUTC + c], acc);
        if (c == 0) atomicAdd(&pcnt[gprev], (float)cnt);
    }
    part[(size_t)p * 256 + c]       = s;    // zeros for out-of-range tiles
    part[(size_t)p * 256 + 128 + c] = s2;
}

// one block per stat-slot (256 blocks); threads stride over NPART; LDS tree; direct store
__global__ __launch_bounds__(256) void k_stats_red(const double* part, double* stats) {
    __shared__ double red[256];
    int t = threadIdx.x;
    int slot = blockIdx.x;                  // 0..255
    double s = 0.0;
    for (int p = t; p < NPART; p += 256) s += part[(size_t)p * 256 + slot];
    red[t] = s;
    __syncthreads();
    for (int o = 128; o > 0; o >>= 1) {
        if (t < o) red[t] += red[t + o];
        __syncthreads();
    }
    if (t == 0) stats[slot] = red[0];       // direct store, no atomic
}

// ---------------- output: affine + mean + L2 normalize ----------------

__global__ __launch_bounds__(128) void k_out(const float* psum, const float* pcnt,
                                             const float* a2, const float* d2,
                                             float* out) {
    int g = blockIdx.x;
    int c = threadIdx.x;
    float cnt = fmaxf(pcnt[g], 1.0f);
    float m = fmaf(psum[g * OUTC + c] / cnt, a2[c], d2[c]);
    float ss = m * m;
#pragma unroll
    for (int o = 1; o < 64; o <<= 1) ss += __shfl_xor(ss, o);
    __shared__ float ws[2];
    if ((c & 63) == 0) ws[c >> 6] = ss;
    __syncthreads();
    float nrm = sqrtf(ws[0] + ws[1]);
    out[g * OUTC + c] = m / fmaxf(nrm, 1e-12f);
}

// ---------------- launch ----------------

extern "C" void kernel_launch(void* const* d_in, const int* in_sizes, int n_in,
                              void* d_out, int out_size, void* d_ws, size_t ws_size,
                              hipStream_t stream) {
    const float* x   = (const float*)d_in[0];
    const float* W1  = (const float*)d_in[1];
    const float* g1  = (const float*)d_in[3];
    const float* be1 = (const float*)d_in[4];
    const float* W2  = (const float*)d_in[5];
    const float* g2  = (const float*)d_in[7];
    const float* be2 = (const float*)d_in[8];
    const int* ei    = (const int*)d_in[9];
    const int* batch = (const int*)d_in[10];
    const int* src = ei;
    const int* dst = ei + N_EDGES;
    float* out = (float*)d_out;

    char* ws = (char*)d_ws;
    size_t off = 0;
    auto alloc = [&](size_t b) {
        char* p = ws + off;
        off = (off + b + 255) & ~(size_t)255;
        return p;
    };
    float*  dis   = (float*)alloc((size_t)N_NODES * 4);
    int*    degi  = (int*)  alloc((size_t)N_NODES * 4);
    int*    curs  = (int*)  alloc((size_t)N_NODES * 4);
    int*    exloc = (int*)  alloc((size_t)N_NODES * 4);
    int*    rowst = (int*)  alloc((size_t)N_NODES * 4);
    int*    bsum  = (int*)  alloc((size_t)NSCAN * 4);
    int2*   csr   = (int2*) alloc((size_t)N_EDGES * 8);
    float*  aggx  = (float*)alloc((size_t)N_NODES * INC * 4);
    ushort* z     = (ushort*)alloc((size_t)N_NODES * OUTC * 2);
    ushort* w2t   = (ushort*)alloc((size_t)HID * OUTC * 2);
    float*  agg2  = (float*)alloc((size_t)N_NODES * OUTC * 4);
    double* part  = (double*)alloc((size_t)NPART * 256 * 8);
    double* st1   = (double*)alloc(2 * HID * 8);
    double* st2   = (double*)alloc(2 * OUTC * 8);
    float*  a1    = (float*)alloc(HID * 4);
    float*  d1    = (float*)alloc(HID * 4);
    float*  a2    = (float*)alloc(OUTC * 4);
    float*  d2    = (float*)alloc(OUTC * 4);
    float*  psum  = (float*)alloc((size_t)N_GRAPH * OUTC * 4);
    float*  pcnt  = (float*)alloc((size_t)N_GRAPH * 4);

    hipMemsetAsync(degi, 0, (size_t)N_NODES * 4, stream);
    hipMemsetAsync(curs, 0, (size_t)N_NODES * 4, stream);
    hipMemsetAsync(st1, 0, 2 * HID * 8, stream);
    hipMemsetAsync(psum, 0, (size_t)N_GRAPH * OUTC * 4, stream);
    hipMemsetAsync(pcnt, 0, (size_t)N_GRAPH * 4, stream);

    k_hist<<<(N_EDGES + 255) / 256, 256, 0, stream>>>(dst, degi);
    k_scan1<<<NSCAN, 256, 0, stream>>>(degi, exloc, bsum, dis);
    k_scan2<<<1, 64, 0, stream>>>(bsum);
    k_scan3<<<(N_NODES + 255) / 256, 256, 0, stream>>>(exloc, bsum, rowst);
    k_scatter<<<(N_EDGES + 255) / 256, 256, 0, stream>>>(src, dst, dis, rowst, curs, csr);
    k_w2t<<<(HID * OUTC + 255) / 256, 256, 0, stream>>>(W2, w2t);
    k_gather9<<<(N_NODES + 27) / 28, 256, 0, stream>>>(x, dis, rowst, degi, csr, aggx);
    k_stats1<<<(N_NODES + 127) / 128, 256, 0, stream>>>(aggx, W1, st1);
    k_finalize<<<1, HID, 0, stream>>>(st1, g1, be1, a1, d1, HID);
    k_gemm2_mfma<<<(N_NODES + 63) / 64, 256, 0, stream>>>(aggx, W1, w2t, a1, d1, z);
    k_gather128<<<(N_NODES + 15) / 16, 256, 0, stream>>>(z, dis, rowst, degi, csr, agg2);
    k_stats_pool<<<SP_BLOCKS, 256, 0, stream>>>(agg2, batch, part, psum, pcnt);
    k_stats_red<<<256, 256, 0, stream>>>(part, st2);
    k_finalize<<<1, OUTC, 0, stream>>>(st2, g2, be2, a2, d2, OUTC);
    k_out<<<N_GRAPH, OUTC, 0, stream>>>(psum, pcnt, a2, d2, out);
}

// Round 15
// 392.981 us; speedup vs baseline: 1.3211x; 1.1120x over previous
//
#include <hip/hip_runtime.h>

#define N_NODES 100000
#define N_EDGES 1600000
#define N_GRAPH 2000
#define INC 9
#define HID 256
#define OUTC 128
#define BN_EPS 1e-5f
#define SCAN_CHUNK 1024
#define NSCAN ((N_NODES + SCAN_CHUNK - 1) / SCAN_CHUNK)
#define SP_NODES 64
#define SP_BLOCKS ((N_NODES + SP_NODES - 1) / SP_NODES)   // 1563
#define NPART (2 * SP_BLOCKS)                              // 3126

typedef unsigned int uint;
typedef unsigned short ushort;
typedef short bf16x8 __attribute__((ext_vector_type(8)));
typedef float f32x4 __attribute__((ext_vector_type(4)));

static __device__ inline ushort f2bf(float f) {
    uint u = __float_as_uint(f);
    uint r = (u + 0x7fffu + ((u >> 16) & 1u)) >> 16;
    return (ushort)r;
}
static __device__ inline float bflo(uint p) { return __uint_as_float(p << 16); }
static __device__ inline float bfhi(uint p) { return __uint_as_float(p & 0xffff0000u); }

// ---------------- CSR build ----------------

// hist also records each edge's within-row slot (atomicAdd return) -> scatter needs no atomics
__global__ __launch_bounds__(256) void k_hist(const int* dst, int* degi, int* pose) {
    int e = blockIdx.x * 256 + threadIdx.x;
    if (e < N_EDGES) pose[e] = atomicAdd(&degi[dst[e]], 1);
}

// scan1 also computes dis = rsqrt(deg+1)
__global__ __launch_bounds__(256) void k_scan1(const int* degi, int* exloc, int* bsum,
                                               float* dis) {
    __shared__ int s[SCAN_CHUNK];
    int t = threadIdx.x;
    int base = blockIdx.x * SCAN_CHUNK;
#pragma unroll
    for (int j = 0; j < 4; ++j) {
        int i = t + j * 256;
        int gi = base + i;
        int dv = (gi < N_NODES) ? degi[gi] : 0;
        s[i] = dv;
        if (gi < N_NODES) dis[gi] = rsqrtf((float)(dv + 1));
    }
    __syncthreads();
    for (int off = 1; off < SCAN_CHUNK; off <<= 1) {
        int v_[4];
#pragma unroll
        for (int j = 0; j < 4; ++j) {
            int i = t + j * 256;
            v_[j] = (i >= off) ? s[i - off] : 0;
        }
        __syncthreads();
#pragma unroll
        for (int j = 0; j < 4; ++j) s[t + j * 256] += v_[j];
        __syncthreads();
    }
#pragma unroll
    for (int j = 0; j < 4; ++j) {
        int i = t + j * 256;
        int gi = base + i;
        if (gi < N_NODES) exloc[gi] = i ? s[i - 1] : 0;
    }
    if (t == 0) bsum[blockIdx.x] = s[SCAN_CHUNK - 1];
}

__global__ void k_scan2(int* bsum) {
    if (threadIdx.x == 0 && blockIdx.x == 0) {
        int acc = 0;
        for (int i = 0; i < NSCAN; ++i) { int v = bsum[i]; bsum[i] = acc; acc += v; }
    }
}

__global__ __launch_bounds__(256) void k_scan3(const int* exloc, const int* bsum,
                                               int* row_start) {
    int v = blockIdx.x * 256 + threadIdx.x;
    if (v < N_NODES) row_start[v] = exloc[v] + bsum[v >> 10];
}

// AoS CSR: one 8B store per edge {src, weight}; slot precomputed in k_hist (no atomics)
__global__ __launch_bounds__(256) void k_scatter(const int* src, const int* dst,
                                                 const float* dis, const int* row_start,
                                                 const int* pose, int2* csr) {
    int e = blockIdx.x * 256 + threadIdx.x;
    if (e < N_EDGES) {
        int s = src[e], d = dst[e];
        int pos = row_start[d] + pose[e];
        csr[pos] = make_int2(s, __float_as_int(dis[s] * dis[d]));
    }
}

// ---------------- W2 transpose + bf16 convert (once per call) ----------------

__global__ __launch_bounds__(256) void k_w2t(const float* W2, ushort* W2Tg) {
    int i = blockIdx.x * 256 + threadIdx.x;       // [0, HID*OUTC)
    if (i < HID * OUTC) {
        int col = i >> 8;        // OUTC index
        int k = i & 255;         // HID index
        W2Tg[i] = f2bf(W2[k * OUTC + col]);
    }
}

// ---------------- conv1 aggregation (gather, 9-wide, self fused) ----------------

__global__ __launch_bounds__(256) void k_gather9(const float* x, const float* dis,
                                                 const int* row_start, const int* degi,
                                                 const int2* csr,
                                                 float* aggx) {
    int t = threadIdx.x;
    if (t >= 252) return;
    int v = blockIdx.x * 28 + t / 9;
    if (v >= N_NODES) return;
    int c = t % 9;
    float w = dis[v];
    float acc = w * w * x[v * INC + c];
    int r0 = row_start[v], dn = degi[v];
    for (int e = 0; e < dn; ++e) {
        int2 ed = csr[r0 + e];
        acc = fmaf(__int_as_float(ed.y), x[ed.x * INC + c], acc);
    }
    aggx[v * INC + c] = acc;
}

// ---------------- BN1 stats: recompute h1 = aggx @ W1 on the fly ----------------

__global__ __launch_bounds__(256) void k_stats1(const float* aggx, const float* W1,
                                                double* stats) {
    __shared__ float sx[128][INC];
    int c = threadIdx.x;
    int v0 = blockIdx.x * 128;
    for (int i = threadIdx.x; i < 128 * INC; i += 256) {
        int vv = i / INC, cc = i % INC;
        int v = v0 + vv;
        sx[vv][cc] = (v < N_NODES) ? aggx[v * INC + cc] : 0.0f;
    }
    __syncthreads();
    float w[INC];
#pragma unroll
    for (int k = 0; k < INC; ++k) w[k] = W1[k * HID + c];
    double s = 0.0, s2 = 0.0;
    int nmax = min(128, N_NODES - v0);
    for (int n = 0; n < nmax; ++n) {
        float h = 0.0f;
#pragma unroll
        for (int k = 0; k < INC; ++k) h = fmaf(sx[n][k], w[k], h);
        s += (double)h;
        s2 += (double)h * (double)h;
    }
    atomicAdd(&stats[c], s);
    atomicAdd(&stats[HID + c], s2);
}

__global__ void k_finalize(const double* stats, const float* g, const float* be,
                           float* a, float* d, int C) {
    int c = blockIdx.x * blockDim.x + threadIdx.x;
    if (c < C) {
        const double invN = 1.0 / (double)N_NODES;
        float mean = (float)(stats[c] * invN);
        float ex2  = (float)(stats[C + c] * invN);
        float var  = ex2 - mean * mean;
        float istd = rsqrtf(var + BN_EPS);
        a[c] = istd * g[c];
        d[c] = be[c] - mean * istd * g[c];
    }
}

// ---------------- GEMM2 (MFMA): z = relu(bn1(aggx@W1)) @ W2, bf16 in/out -------------

#define HPAD 88

__global__ __launch_bounds__(256) void k_gemm2_mfma(const float* aggx, const float* W1,
                                                    const ushort* W2Tg, const float* a1,
                                                    const float* d1, ushort* z) {
    __shared__ __align__(16) unsigned char smem[47616];
    ushort* sHb  = (ushort*)(smem);                 // [64][88]  11264 B
    ushort* sW2T = (ushort*)(smem + 11264);         // [128][88] 22528 B
    float*  sW1f = (float*) (smem + 33792);         // [9*256]    9216 B
    float*  sA   = (float*) (smem + 43008);         // [64][9]    2304 B
    float*  sa1  = (float*) (smem + 45312);         // [256]      1024 B
    float*  sd1  = (float*) (smem + 46336);         // [256]      1024 B

    int t = threadIdx.x;
    int v0 = blockIdx.x * 64;

    for (int i = t; i < INC * HID; i += 256) sW1f[i] = W1[i];
    sa1[t] = a1[t & 255];
    sd1[t] = d1[t & 255];
    for (int i = t; i < 64 * INC; i += 256) {
        int vv = i / INC, cc = i % INC;
        int v = v0 + vv;
        sA[i] = (v < N_NODES) ? aggx[v * INC + cc] : 0.0f;
    }
    __syncthreads();

    int row = t >> 2, q = t & 3;
    int wave = t >> 6, lane = t & 63;
    int lr = lane & 15, lq = lane >> 4;

    float ax[INC];
#pragma unroll
    for (int k = 0; k < INC; ++k) ax[k] = sA[row * INC + k];

    f32x4 acc[8];
#pragma unroll
    for (int ct = 0; ct < 8; ++ct) acc[ct] = (f32x4){0.f, 0.f, 0.f, 0.f};

    for (int k0 = 0; k0 < HID; k0 += 64) {
#pragma unroll
        for (int i = 0; i < 4; ++i) {
            int idx = t + i * 256;
            int col = idx >> 3, sub = idx & 7;
            *(uint4*)&sW2T[col * HPAD + sub * 8] =
                *(const uint4*)&W2Tg[col * HID + k0 + sub * 8];
        }
#pragma unroll
        for (int jj = 0; jj < 8; ++jj) {
            int gc = k0 + q * 16 + jj * 2;
            float h0 = 0.f, h1 = 0.f;
#pragma unroll
            for (int k = 0; k < INC; ++k) {
                h0 = fmaf(ax[k], sW1f[k * HID + gc], h0);
                h1 = fmaf(ax[k], sW1f[k * HID + gc + 1], h1);
            }
            float hn0 = fmaxf(fmaf(h0, sa1[gc], sd1[gc]), 0.f);
            float hn1 = fmaxf(fmaf(h1, sa1[gc + 1], sd1[gc + 1]), 0.f);
            uint pk = (uint)f2bf(hn0) | ((uint)f2bf(hn1) << 16);
            *(uint*)&sHb[row * HPAD + q * 16 + jj * 2] = pk;
        }
        __syncthreads();
        int arow = (wave * 16 + lr) * HPAD + lq * 8;
        bf16x8 a0 = *(const bf16x8*)&sHb[arow];
        bf16x8 a1v = *(const bf16x8*)&sHb[arow + 32];
#pragma unroll
        for (int ct = 0; ct < 8; ++ct) {
            int brow = (ct * 16 + lr) * HPAD + lq * 8;
            bf16x8 b0 = *(const bf16x8*)&sW2T[brow];
            bf16x8 b1 = *(const bf16x8*)&sW2T[brow + 32];
            acc[ct] = __builtin_amdgcn_mfma_f32_16x16x32_bf16(a0, b0, acc[ct], 0, 0, 0);
            acc[ct] = __builtin_amdgcn_mfma_f32_16x16x32_bf16(a1v, b1, acc[ct], 0, 0, 0);
        }
        __syncthreads();
    }

    ushort* stage = (ushort*)smem;                  // [64][128]
#pragma unroll
    for (int ct = 0; ct < 8; ++ct)
#pragma unroll
        for (int r = 0; r < 4; ++r)
            stage[(wave * 16 + lq * 4 + r) * 128 + ct * 16 + lr] = f2bf(acc[ct][r]);
    __syncthreads();
#pragma unroll
    for (int i = 0; i < 4; ++i) {
        int idx = t + i * 256;
        int rr = idx >> 4, sub = idx & 15;
        int v = v0 + rr;
        if (v < N_NODES)
            *(uint4*)&z[(size_t)v * OUTC + sub * 8] =
                *(const uint4*)&stage[rr * 128 + sub * 8];
    }
}

// ---------------- conv2 aggregation (gather, bf16 z, 16 rows x 16 lanes) ----------------

__global__ __launch_bounds__(256) void k_gather128(const ushort* z, const float* dis,
                                                   const int* row_start, const int* degi,
                                                   const int2* csr,
                                                   float* agg2) {
    int t = threadIdx.x;
    int v = blockIdx.x * 16 + (t >> 4);
    if (v >= N_NODES) return;
    int c0 = (t & 15) * 8;

    float acc[8];
    float dv = dis[v];
    float w2 = dv * dv;
    uint4 zv = *(const uint4*)&z[(size_t)v * OUTC + c0];
    acc[0] = w2 * bflo(zv.x); acc[1] = w2 * bfhi(zv.x);
    acc[2] = w2 * bflo(zv.y); acc[3] = w2 * bfhi(zv.y);
    acc[4] = w2 * bflo(zv.z); acc[5] = w2 * bfhi(zv.z);
    acc[6] = w2 * bflo(zv.w); acc[7] = w2 * bfhi(zv.w);

    int r0 = row_start[v], dn = degi[v];
    for (int e = 0; e < dn; ++e) {
        int2 ed = csr[r0 + e];
        float ew = __int_as_float(ed.y);
        uint4 sv = *(const uint4*)&z[(size_t)ed.x * OUTC + c0];
        acc[0] = fmaf(ew, bflo(sv.x), acc[0]);
        acc[1] = fmaf(ew, bfhi(sv.x), acc[1]);
        acc[2] = fmaf(ew, bflo(sv.y), acc[2]);
        acc[3] = fmaf(ew, bfhi(sv.y), acc[3]);
        acc[4] = fmaf(ew, bflo(sv.z), acc[4]);
        acc[5] = fmaf(ew, bfhi(sv.z), acc[5]);
        acc[6] = fmaf(ew, bflo(sv.w), acc[6]);
        acc[7] = fmaf(ew, bfhi(sv.w), acc[7]);
    }
    float4 lo = make_float4(acc[0], acc[1], acc[2], acc[3]);
    float4 hi = make_float4(acc[4], acc[5], acc[6], acc[7]);
    *(float4*)&agg2[(size_t)v * OUTC + c0] = lo;
    *(float4*)&agg2[(size_t)v * OUTC + c0 + 4] = hi;
}

// ---------------- fused BN2 stats + pool: partials to scratch (no hot atomics) --------

__global__ __launch_bounds__(256) void k_stats_pool(const float* agg2, const int* batch,
                                                    double* part, float* psum, float* pcnt) {
    int t = threadIdx.x;
    int c = t & 127;
    int half = t >> 7;                      // 0 or 1
    int p = blockIdx.x * 2 + half;
    int v0 = blockIdx.x * SP_NODES + half * (SP_NODES / 2);
    double s = 0.0, s2 = 0.0;
    if (v0 < N_NODES) {
        int vend = min(v0 + SP_NODES / 2, N_NODES);
        float acc = 0.0f;
        int cnt = 0;
        int gprev = batch[v0];
        for (int v = v0; v < vend; ++v) {
            float h = agg2[(size_t)v * OUTC + c];
            s += (double)h;
            s2 += (double)h * (double)h;
            int g = batch[v];
            if (g != gprev) {
                atomicAdd(&psum[gprev * OUTC + c], acc);
                if (c == 0) atomicAdd(&pcnt[gprev], (float)cnt);
                acc = 0.0f; cnt = 0; gprev = g;
            }
            acc += h;
            cnt++;
        }
        atomicAdd(&psum[gprev * OUTC + c], acc);
        if (c == 0) atomicAdd(&pcnt[gprev], (float)cnt);
    }
    part[(size_t)p * 256 + c]       = s;    // zeros for out-of-range tiles
    part[(size_t)p * 256 + 128 + c] = s2;
}

// one block per stat-slot (256 blocks); threads stride over NPART; LDS tree; direct store
__global__ __launch_bounds__(256) void k_stats_red(const double* part, double* stats) {
    __shared__ double red[256];
    int t = threadIdx.x;
    int slot = blockIdx.x;                  // 0..255
    double s = 0.0;
    for (int p = t; p < NPART; p += 256) s += part[(size_t)p * 256 + slot];
    red[t] = s;
    __syncthreads();
    for (int o = 128; o > 0; o >>= 1) {
        if (t < o) red[t] += red[t + o];
        __syncthreads();
    }
    if (t == 0) stats[slot] = red[0];       // direct store, no atomic
}

// ---------------- output: affine + mean + L2 normalize ----------------

__global__ __launch_bounds__(128) void k_out(const float* psum, const float* pcnt,
                                             const float* a2, const float* d2,
                                             float* out) {
    int g = blockIdx.x;
    int c = threadIdx.x;
    float cnt = fmaxf(pcnt[g], 1.0f);
    float m = fmaf(psum[g * OUTC + c] / cnt, a2[c], d2[c]);
    float ss = m * m;
#pragma unroll
    for (int o = 1; o < 64; o <<= 1) ss += __shfl_xor(ss, o);
    __shared__ float ws[2];
    if ((c & 63) == 0) ws[c >> 6] = ss;
    __syncthreads();
    float nrm = sqrtf(ws[0] + ws[1]);
    out[g * OUTC + c] = m / fmaxf(nrm, 1e-12f);
}

// ---------------- launch ----------------

extern "C" void kernel_launch(void* const* d_in, const int* in_sizes, int n_in,
                              void* d_out, int out_size, void* d_ws, size_t ws_size,
                              hipStream_t stream) {
    const float* x   = (const float*)d_in[0];
    const float* W1  = (const float*)d_in[1];
    const float* g1  = (const float*)d_in[3];
    const float* be1 = (const float*)d_in[4];
    const float* W2  = (const float*)d_in[5];
    const float* g2  = (const float*)d_in[7];
    const float* be2 = (const float*)d_in[8];
    const int* ei    = (const int*)d_in[9];
    const int* batch = (const int*)d_in[10];
    const int* src = ei;
    const int* dst = ei + N_EDGES;
    float* out = (float*)d_out;

    char* ws = (char*)d_ws;
    size_t off = 0;
    auto alloc = [&](size_t b) {
        char* p = ws + off;
        off = (off + b + 255) & ~(size_t)255;
        return p;
    };
    float*  dis   = (float*)alloc((size_t)N_NODES * 4);
    int*    degi  = (int*)  alloc((size_t)N_NODES * 4);
    int*    pose  = (int*)  alloc((size_t)N_EDGES * 4);
    int*    exloc = (int*)  alloc((size_t)N_NODES * 4);
    int*    rowst = (int*)  alloc((size_t)N_NODES * 4);
    int*    bsum  = (int*)  alloc((size_t)NSCAN * 4);
    int2*   csr   = (int2*) alloc((size_t)N_EDGES * 8);
    float*  aggx  = (float*)alloc((size_t)N_NODES * INC * 4);
    ushort* z     = (ushort*)alloc((size_t)N_NODES * OUTC * 2);
    ushort* w2t   = (ushort*)alloc((size_t)HID * OUTC * 2);
    float*  agg2  = (float*)alloc((size_t)N_NODES * OUTC * 4);
    double* part  = (double*)alloc((size_t)NPART * 256 * 8);
    double* st1   = (double*)alloc(2 * HID * 8);
    double* st2   = (double*)alloc(2 * OUTC * 8);
    float*  a1    = (float*)alloc(HID * 4);
    float*  d1    = (float*)alloc(HID * 4);
    float*  a2    = (float*)alloc(OUTC * 4);
    float*  d2    = (float*)alloc(OUTC * 4);
    float*  psum  = (float*)alloc((size_t)N_GRAPH * OUTC * 4);
    float*  pcnt  = (float*)alloc((size_t)N_GRAPH * 4);

    hipMemsetAsync(degi, 0, (size_t)N_NODES * 4, stream);
    hipMemsetAsync(st1, 0, 2 * HID * 8, stream);
    hipMemsetAsync(psum, 0, (size_t)N_GRAPH * OUTC * 4, stream);
    hipMemsetAsync(pcnt, 0, (size_t)N_GRAPH * 4, stream);

    k_hist<<<(N_EDGES + 255) / 256, 256, 0, stream>>>(dst, degi, pose);
    k_scan1<<<NSCAN, 256, 0, stream>>>(degi, exloc, bsum, dis);
    k_scan2<<<1, 64, 0, stream>>>(bsum);
    k_scan3<<<(N_NODES + 255) / 256, 256, 0, stream>>>(exloc, bsum, rowst);
    k_scatter<<<(N_EDGES + 255) / 256, 256, 0, stream>>>(src, dst, dis, rowst, pose, csr);
    k_w2t<<<(HID * OUTC + 255) / 256, 256, 0, stream>>>(W2, w2t);
    k_gather9<<<(N_NODES + 27) / 28, 256, 0, stream>>>(x, dis, rowst, degi, csr, aggx);
    k_stats1<<<(N_NODES + 127) / 128, 256, 0, stream>>>(aggx, W1, st1);
    k_finalize<<<1, HID, 0, stream>>>(st1, g1, be1, a1, d1, HID);
    k_gemm2_mfma<<<(N_NODES + 63) / 64, 256, 0, stream>>>(aggx, W1, w2t, a1, d1, z);
    k_gather128<<<(N_NODES + 15) / 16, 256, 0, stream>>>(z, dis, rowst, degi, csr, agg2);
    k_stats_pool<<<SP_BLOCKS, 256, 0, stream>>>(agg2, batch, part, psum, pcnt);
    k_stats_red<<<256, 256, 0, stream>>>(part, st2);
    k_finalize<<<1, OUTC, 0, stream>>>(st2, g2, be2, a2, d2, OUTC);
    k_out<<<N_GRAPH, OUTC, 0, stream>>>(psum, pcnt, a2, d2, out);
}